// Round 3
// baseline (367.265 us; speedup 1.0000x reference)
//
#include <hip/hip_runtime.h>
#include <hip/hip_bf16.h>

#define RELS 7
#define DIM 64
#define KTOT 512  // 7*64 + 64 (root)

typedef __attribute__((ext_vector_type(8))) short short8;
typedef __attribute__((ext_vector_type(4))) float floatx4;

__device__ inline unsigned short f2b(float f) {
  union { float f; unsigned u; } v; v.f = f;
  unsigned u = v.u + 0x7fffu + ((v.u >> 16) & 1u);  // round-nearest-even
  return (unsigned short)(u >> 16);
}
__device__ inline float b2f(unsigned short b) {
  union { unsigned u; float f; } v; v.u = ((unsigned)b) << 16;
  return v.f;
}

// x f32 -> bf16 (8 elems/thread)
__global__ void __launch_bounds__(256) k_xb(const float* __restrict__ x,
                                            unsigned short* __restrict__ xb, long n8) {
  long t = (long)blockIdx.x * 256 + threadIdx.x;
  if (t >= n8) return;
  const float4* p = reinterpret_cast<const float4*>(x + t * 8);
  float4 f0 = p[0], f1 = p[1];
  short8 o;
  o[0] = (short)f2b(f0.x); o[1] = (short)f2b(f0.y);
  o[2] = (short)f2b(f0.z); o[3] = (short)f2b(f0.w);
  o[4] = (short)f2b(f1.x); o[5] = (short)f2b(f1.y);
  o[6] = (short)f2b(f1.z); o[7] = (short)f2b(f1.w);
  *reinterpret_cast<short8*>(xb + t * 8) = o;
}

// histogram over (dst*8 + rel)
__global__ void __launch_bounds__(256) k_hist(const int* __restrict__ dst,
                                              const int* __restrict__ et,
                                              int* __restrict__ deg, int E) {
  int e = blockIdx.x * 256 + threadIdx.x;
  if (e < E) atomicAdd(&deg[(dst[e] << 3) + et[e]], 1);
}

// block-local exclusive scan over 1024 entries (256 thr x 4)
__global__ void __launch_bounds__(256) k_scan1(const int* __restrict__ deg,
                                               int* __restrict__ start,
                                               int* __restrict__ bsum, int n) {
  __shared__ int sm[256];
  int t = threadIdx.x;
  int base = blockIdx.x * 1024 + t * 4;
  int v0 = (base + 0 < n) ? deg[base + 0] : 0;
  int v1 = (base + 1 < n) ? deg[base + 1] : 0;
  int v2 = (base + 2 < n) ? deg[base + 2] : 0;
  int v3 = (base + 3 < n) ? deg[base + 3] : 0;
  int s = v0 + v1 + v2 + v3;
  sm[t] = s;
  __syncthreads();
  for (int off = 1; off < 256; off <<= 1) {
    int a = (t >= off) ? sm[t - off] : 0;
    __syncthreads();
    sm[t] += a;
    __syncthreads();
  }
  int excl = sm[t] - s;
  if (base + 0 < n) start[base + 0] = excl;
  excl += v0;
  if (base + 1 < n) start[base + 1] = excl;
  excl += v1;
  if (base + 2 < n) start[base + 2] = excl;
  excl += v2;
  if (base + 3 < n) start[base + 3] = excl;
  if (t == 255) bsum[blockIdx.x] = sm[255];
}

// single-block exclusive scan over up to 1024 block sums (in place)
__global__ void __launch_bounds__(256) k_scan2(int* bsum, int nb) {
  __shared__ int sm[256];
  int t = threadIdx.x;
  int base = t * 4;
  int v0 = (base + 0 < nb) ? bsum[base + 0] : 0;
  int v1 = (base + 1 < nb) ? bsum[base + 1] : 0;
  int v2 = (base + 2 < nb) ? bsum[base + 2] : 0;
  int v3 = (base + 3 < nb) ? bsum[base + 3] : 0;
  int s = v0 + v1 + v2 + v3;
  sm[t] = s;
  __syncthreads();
  for (int off = 1; off < 256; off <<= 1) {
    int a = (t >= off) ? sm[t - off] : 0;
    __syncthreads();
    sm[t] += a;
    __syncthreads();
  }
  int excl = sm[t] - s;
  if (base + 0 < nb) bsum[base + 0] = excl;
  excl += v0;
  if (base + 1 < nb) bsum[base + 1] = excl;
  excl += v1;
  if (base + 2 < nb) bsum[base + 2] = excl;
  excl += v2;
  if (base + 3 < nb) bsum[base + 3] = excl;
}

__global__ void __launch_bounds__(256) k_scan3(int* __restrict__ start,
                                               int* __restrict__ cursor,
                                               const int* __restrict__ bsum,
                                               int n, int E) {
  int i = blockIdx.x * 256 + threadIdx.x;
  if (i < n) {
    int v = start[i] + bsum[i >> 10];
    start[i] = v;
    cursor[i] = v;
  } else if (i == n) {
    start[n] = E;
  }
}

__global__ void __launch_bounds__(256) k_bucket(const int* __restrict__ ei,
                                                const int* __restrict__ et,
                                                int* __restrict__ cursor,
                                                int* __restrict__ esrc, int E) {
  int e = blockIdx.x * 256 + threadIdx.x;
  if (e >= E) return;
  int s = ei[e], d = ei[E + e], r = et[e];
  int pos = atomicAdd(&cursor[(d << 3) + r], 1);
  esrc[pos] = s;
}

// one wave per (dst, rel) segment: mean of gathered bf16 x rows
__global__ void __launch_bounds__(256) k_seg(const int* __restrict__ start,
                                             const int* __restrict__ esrc,
                                             const unsigned short* __restrict__ xb,
                                             unsigned short* __restrict__ mn, int N) {
  long w = ((long)blockIdx.x * 256 + threadIdx.x) >> 6;  // segment id = dst*8 + r
  int lane = threadIdx.x & 63;
  int r = (int)(w & 7);
  long node = w >> 3;
  if (node >= N || r == RELS) return;
  int a = start[w], b = start[w + 1];
  float acc = 0.0f;
  for (int e = a; e < b; ++e) {
    int src = esrc[e];
    acc += b2f(xb[((long)src << 6) + lane]);
  }
  float inv = __builtin_amdgcn_rcpf(fmaxf((float)(b - a), 1.0f));
  mn[(node * RELS + r) * DIM + lane] = f2b(acc * inv);
}

// out[i][:] = [mn[i] | xb[i]] (K=512, bf16) @ [W;root] + bias
__global__ void __launch_bounds__(256) k_gemm(const unsigned short* __restrict__ mn,
                                              const unsigned short* __restrict__ xb,
                                              const float* __restrict__ W,
                                              const float* __restrict__ root,
                                              const float* __restrict__ bias,
                                              float* __restrict__ out, int N)
{
  __shared__ short Bl[KTOT * DIM];  // 64 KiB, MFMA-fragment order
  const int tid = threadIdx.x;

  for (int g = tid; g < 4096; g += 256) {
    int kb = g >> 6, col = g & 63;
    short8 tmp;
#pragma unroll
    for (int j = 0; j < 8; ++j) {
      int k = kb * 8 + j;
      float w = (k < 448) ? W[k * 64 + col] : root[(k - 448) * 64 + col];
      tmp[j] = (short)f2b(w);
    }
    *reinterpret_cast<short8*>(&Bl[g * 8]) = tmp;
  }
  __syncthreads();

  const int lane = tid & 63;
  const int wv = tid >> 6;
  const int rowbase = blockIdx.x * 64 + wv * 16;
  const int row16 = lane & 15;
  const int kg = lane >> 4;
  int i = rowbase + row16;
  if (i > N - 1) i = N - 1;

  floatx4 c0 = {0,0,0,0}, c1 = {0,0,0,0}, c2 = {0,0,0,0}, c3 = {0,0,0,0};
  const short8* Bv = reinterpret_cast<const short8*>(Bl);

#pragma unroll
  for (int kk = 0; kk < 16; ++kk) {
    const int r = kk >> 1;
    const int d0 = (kk * 32 + kg * 8) & 63;
    const unsigned short* ap = (r < RELS)
        ? (mn + (long)i * (RELS * DIM) + r * DIM + d0)
        : (xb + (long)i * DIM + d0);
    short8 aa = *reinterpret_cast<const short8*>(ap);
    const int bb = (kk * 4 + kg) * 64 + row16;
    c0 = __builtin_amdgcn_mfma_f32_16x16x32_bf16(aa, Bv[bb],      c0, 0, 0, 0);
    c1 = __builtin_amdgcn_mfma_f32_16x16x32_bf16(aa, Bv[bb + 16], c1, 0, 0, 0);
    c2 = __builtin_amdgcn_mfma_f32_16x16x32_bf16(aa, Bv[bb + 32], c2, 0, 0, 0);
    c3 = __builtin_amdgcn_mfma_f32_16x16x32_bf16(aa, Bv[bb + 48], c3, 0, 0, 0);
  }

  const int rowoff = kg * 4;
#pragma unroll
  for (int t = 0; t < 4; ++t) {
    floatx4 c = (t == 0) ? c0 : (t == 1) ? c1 : (t == 2) ? c2 : c3;
    const int col = t * 16 + row16;
    const float b = bias[col];
#pragma unroll
    for (int q = 0; q < 4; ++q) {
      int row = rowbase + rowoff + q;
      if (row < N) out[(long)row * DIM + col] = c[q] + b;
    }
  }
}

extern "C" void kernel_launch(void* const* d_in, const int* in_sizes, int n_in,
                              void* d_out, int out_size, void* d_ws, size_t ws_size,
                              hipStream_t stream)
{
  const float* x    = (const float*)d_in[0];
  const float* W    = (const float*)d_in[1];
  const float* root = (const float*)d_in[2];
  const float* bias = (const float*)d_in[3];
  const int*   ei   = (const int*)d_in[4];
  const int*   et   = (const int*)d_in[5];
  float* out = (float*)d_out;

  const int N = in_sizes[0] / DIM;
  const int E = in_sizes[4] / 2;
  const int NS = N * 8;  // segments = dst*8 + rel (r=7 bucket always empty)

  // workspace layout
  unsigned short* mn = (unsigned short*)d_ws;            // [N][7][64] bf16
  unsigned short* xb = mn + (size_t)N * RELS * DIM;      // [N][64] bf16
  int* esrc   = (int*)(xb + (size_t)N * DIM);            // [E]
  int* deg    = esrc + E;                                // [NS]
  int* start  = deg + NS;                                // [NS+1]
  int* cursor = start + NS + 1;                          // [NS]
  int* bsum   = cursor + NS;                             // [ceil(NS/1024)]

  hipMemsetAsync(deg, 0, (size_t)NS * sizeof(int), stream);
  k_xb<<<(int)(((long)N * DIM / 8 + 255) / 256), 256, 0, stream>>>(x, xb, (long)N * DIM / 8);
  k_hist<<<(E + 255) / 256, 256, 0, stream>>>(ei + E, et, deg, E);
  int nb = (NS + 1023) / 1024;
  k_scan1<<<nb, 256, 0, stream>>>(deg, start, bsum, NS);
  k_scan2<<<1, 256, 0, stream>>>(bsum, nb);
  k_scan3<<<(NS + 1 + 255) / 256, 256, 0, stream>>>(start, cursor, bsum, NS, E);
  k_bucket<<<(E + 255) / 256, 256, 0, stream>>>(ei, et, cursor, esrc, E);
  k_seg<<<N * 2, 256, 0, stream>>>(start, esrc, xb, mn, N);
  k_gemm<<<(N + 63) / 64, 256, 0, stream>>>(mn, xb, W, root, bias, out, N);
}

// Round 4
// 279.847 us; speedup vs baseline: 1.3124x; 1.3124x over previous
//
#include <hip/hip_runtime.h>
#include <hip/hip_bf16.h>

#define RELS 7
#define DIM 64
#define KTOT 512  // 7*64 + 64 (root)

typedef __attribute__((ext_vector_type(8))) short short8;
typedef __attribute__((ext_vector_type(4))) float floatx4;

__device__ inline unsigned short f2b(float f) {
  union { float f; unsigned u; } v; v.f = f;
  unsigned u = v.u + 0x7fffu + ((v.u >> 16) & 1u);  // round-nearest-even
  return (unsigned short)(u >> 16);
}
__device__ inline float b2f(unsigned short b) {
  union { unsigned u; float f; } v; v.u = ((unsigned)b) << 16;
  return v.f;
}

// x f32 -> bf16 (8 elems/thread)
__global__ void __launch_bounds__(256) k_xb(const float* __restrict__ x,
                                            unsigned short* __restrict__ xb, long n8) {
  long t = (long)blockIdx.x * 256 + threadIdx.x;
  if (t >= n8) return;
  const float4* p = reinterpret_cast<const float4*>(x + t * 8);
  float4 f0 = p[0], f1 = p[1];
  short8 o;
  o[0] = (short)f2b(f0.x); o[1] = (short)f2b(f0.y);
  o[2] = (short)f2b(f0.z); o[3] = (short)f2b(f0.w);
  o[4] = (short)f2b(f1.x); o[5] = (short)f2b(f1.y);
  o[6] = (short)f2b(f1.z); o[7] = (short)f2b(f1.w);
  *reinterpret_cast<short8*>(xb + t * 8) = o;
}

// histogram over (dst*8 + rel)
__global__ void __launch_bounds__(256) k_hist(const int* __restrict__ dst,
                                              const int* __restrict__ et,
                                              int* __restrict__ deg, int E) {
  int e = blockIdx.x * 256 + threadIdx.x;
  if (e < E) atomicAdd(&deg[(dst[e] << 3) + et[e]], 1);
}

// block-local exclusive scan over 1024 entries (256 thr x 4)
__global__ void __launch_bounds__(256) k_scan1(const int* __restrict__ deg,
                                               int* __restrict__ start,
                                               int* __restrict__ bsum, int n) {
  __shared__ int sm[256];
  int t = threadIdx.x;
  int base = blockIdx.x * 1024 + t * 4;
  int v0 = (base + 0 < n) ? deg[base + 0] : 0;
  int v1 = (base + 1 < n) ? deg[base + 1] : 0;
  int v2 = (base + 2 < n) ? deg[base + 2] : 0;
  int v3 = (base + 3 < n) ? deg[base + 3] : 0;
  int s = v0 + v1 + v2 + v3;
  sm[t] = s;
  __syncthreads();
  for (int off = 1; off < 256; off <<= 1) {
    int a = (t >= off) ? sm[t - off] : 0;
    __syncthreads();
    sm[t] += a;
    __syncthreads();
  }
  int excl = sm[t] - s;
  if (base + 0 < n) start[base + 0] = excl;
  excl += v0;
  if (base + 1 < n) start[base + 1] = excl;
  excl += v1;
  if (base + 2 < n) start[base + 2] = excl;
  excl += v2;
  if (base + 3 < n) start[base + 3] = excl;
  if (t == 255) bsum[blockIdx.x] = sm[255];
}

// single-block exclusive scan over up to 1024 block sums (in place)
__global__ void __launch_bounds__(256) k_scan2(int* bsum, int nb) {
  __shared__ int sm[256];
  int t = threadIdx.x;
  int base = t * 4;
  int v0 = (base + 0 < nb) ? bsum[base + 0] : 0;
  int v1 = (base + 1 < nb) ? bsum[base + 1] : 0;
  int v2 = (base + 2 < nb) ? bsum[base + 2] : 0;
  int v3 = (base + 3 < nb) ? bsum[base + 3] : 0;
  int s = v0 + v1 + v2 + v3;
  sm[t] = s;
  __syncthreads();
  for (int off = 1; off < 256; off <<= 1) {
    int a = (t >= off) ? sm[t - off] : 0;
    __syncthreads();
    sm[t] += a;
    __syncthreads();
  }
  int excl = sm[t] - s;
  if (base + 0 < nb) bsum[base + 0] = excl;
  excl += v0;
  if (base + 1 < nb) bsum[base + 1] = excl;
  excl += v1;
  if (base + 2 < nb) bsum[base + 2] = excl;
  excl += v2;
  if (base + 3 < nb) bsum[base + 3] = excl;
}

__global__ void __launch_bounds__(256) k_scan3(int* __restrict__ start,
                                               int* __restrict__ cursor,
                                               const int* __restrict__ bsum,
                                               int n, int E) {
  int i = blockIdx.x * 256 + threadIdx.x;
  if (i < n) {
    int v = start[i] + bsum[i >> 10];
    start[i] = v;
    cursor[i] = v;
  } else if (i == n) {
    start[n] = E;
  }
}

__global__ void __launch_bounds__(256) k_bucket(const int* __restrict__ ei,
                                                const int* __restrict__ et,
                                                int* __restrict__ cursor,
                                                int* __restrict__ esrc, int E) {
  int e = blockIdx.x * 256 + threadIdx.x;
  if (e >= E) return;
  int s = ei[e], d = ei[E + e], r = et[e];
  int pos = atomicAdd(&cursor[(d << 3) + r], 1);
  esrc[pos] = s;
}

// one wave per dst node; edges sorted by (dst, rel): bare accumulate per segment
__global__ void __launch_bounds__(256) k_seg(const int* __restrict__ start,
                                             const int* __restrict__ esrc,
                                             const unsigned short* __restrict__ xb,
                                             unsigned short* __restrict__ mn, int N) {
  int node = (int)(((long)blockIdx.x * 256 + threadIdx.x) >> 6);
  int lane = threadIdx.x & 63;
  if (node >= N) return;
  int sv = 0;
  if (lane < 8) sv = start[(node << 3) + lane];  // segment boundaries r=0..7
#pragma unroll
  for (int r = 0; r < RELS; ++r) {
    int a = __shfl(sv, r, 64);
    int b = __shfl(sv, r + 1, 64);
    float acc0 = 0.0f, acc1 = 0.0f;
    int e = a;
    for (; e + 1 < b; e += 2) {
      int s0 = esrc[e], s1 = esrc[e + 1];
      acc0 += b2f(xb[((long)s0 << 6) + lane]);
      acc1 += b2f(xb[((long)s1 << 6) + lane]);
    }
    if (e < b) acc0 += b2f(xb[((long)esrc[e] << 6) + lane]);
    float inv = __builtin_amdgcn_rcpf(fmaxf((float)(b - a), 1.0f));
    mn[((long)node * RELS + r) * DIM + lane] = f2b((acc0 + acc1) * inv);
  }
}

// out[i][:] = [mn[i] | xb[i]] (K=512, bf16) @ [W;root] + bias
__global__ void __launch_bounds__(256) k_gemm(const unsigned short* __restrict__ mn,
                                              const unsigned short* __restrict__ xb,
                                              const float* __restrict__ W,
                                              const float* __restrict__ root,
                                              const float* __restrict__ bias,
                                              float* __restrict__ out, int N)
{
  __shared__ short Bl[KTOT * DIM];  // 64 KiB, MFMA-fragment order
  const int tid = threadIdx.x;

  for (int g = tid; g < 4096; g += 256) {
    int kb = g >> 6, col = g & 63;
    short8 tmp;
#pragma unroll
    for (int j = 0; j < 8; ++j) {
      int k = kb * 8 + j;
      float w = (k < 448) ? W[k * 64 + col] : root[(k - 448) * 64 + col];
      tmp[j] = (short)f2b(w);
    }
    *reinterpret_cast<short8*>(&Bl[g * 8]) = tmp;
  }
  __syncthreads();

  const int lane = tid & 63;
  const int wv = tid >> 6;
  const int rowbase = blockIdx.x * 64 + wv * 16;
  const int row16 = lane & 15;
  const int kg = lane >> 4;
  int i = rowbase + row16;
  if (i > N - 1) i = N - 1;

  floatx4 c0 = {0,0,0,0}, c1 = {0,0,0,0}, c2 = {0,0,0,0}, c3 = {0,0,0,0};
  const short8* Bv = reinterpret_cast<const short8*>(Bl);

#pragma unroll
  for (int kk = 0; kk < 16; ++kk) {
    const int r = kk >> 1;
    const int d0 = (kk * 32 + kg * 8) & 63;
    const unsigned short* ap = (r < RELS)
        ? (mn + (long)i * (RELS * DIM) + r * DIM + d0)
        : (xb + (long)i * DIM + d0);
    short8 aa = *reinterpret_cast<const short8*>(ap);
    const int bb = (kk * 4 + kg) * 64 + row16;
    c0 = __builtin_amdgcn_mfma_f32_16x16x32_bf16(aa, Bv[bb],      c0, 0, 0, 0);
    c1 = __builtin_amdgcn_mfma_f32_16x16x32_bf16(aa, Bv[bb + 16], c1, 0, 0, 0);
    c2 = __builtin_amdgcn_mfma_f32_16x16x32_bf16(aa, Bv[bb + 32], c2, 0, 0, 0);
    c3 = __builtin_amdgcn_mfma_f32_16x16x32_bf16(aa, Bv[bb + 48], c3, 0, 0, 0);
  }

  const int rowoff = kg * 4;
#pragma unroll
  for (int t = 0; t < 4; ++t) {
    floatx4 c = (t == 0) ? c0 : (t == 1) ? c1 : (t == 2) ? c2 : c3;
    const int col = t * 16 + row16;
    const float b = bias[col];
#pragma unroll
    for (int q = 0; q < 4; ++q) {
      int row = rowbase + rowoff + q;
      if (row < N) out[(long)row * DIM + col] = c[q] + b;
    }
  }
}

extern "C" void kernel_launch(void* const* d_in, const int* in_sizes, int n_in,
                              void* d_out, int out_size, void* d_ws, size_t ws_size,
                              hipStream_t stream)
{
  const float* x    = (const float*)d_in[0];
  const float* W    = (const float*)d_in[1];
  const float* root = (const float*)d_in[2];
  const float* bias = (const float*)d_in[3];
  const int*   ei   = (const int*)d_in[4];
  const int*   et   = (const int*)d_in[5];
  float* out = (float*)d_out;

  const int N = in_sizes[0] / DIM;
  const int E = in_sizes[4] / 2;
  const int NS = N * 8;  // segments = dst*8 + rel (r=7 bucket always empty)

  // workspace layout
  unsigned short* mn = (unsigned short*)d_ws;            // [N][7][64] bf16
  unsigned short* xb = mn + (size_t)N * RELS * DIM;      // [N][64] bf16
  int* esrc   = (int*)(xb + (size_t)N * DIM);            // [E]
  int* deg    = esrc + E;                                // [NS]
  int* start  = deg + NS;                                // [NS+1]
  int* cursor = start + NS + 1;                          // [NS]
  int* bsum   = cursor + NS;                             // [ceil(NS/1024)]

  hipMemsetAsync(deg, 0, (size_t)NS * sizeof(int), stream);
  k_xb<<<(int)(((long)N * DIM / 8 + 255) / 256), 256, 0, stream>>>(x, xb, (long)N * DIM / 8);
  k_hist<<<(E + 255) / 256, 256, 0, stream>>>(ei + E, et, deg, E);
  int nb = (NS + 1023) / 1024;
  k_scan1<<<nb, 256, 0, stream>>>(deg, start, bsum, NS);
  k_scan2<<<1, 256, 0, stream>>>(bsum, nb);
  k_scan3<<<(NS + 1 + 255) / 256, 256, 0, stream>>>(start, cursor, bsum, NS, E);
  k_bucket<<<(E + 255) / 256, 256, 0, stream>>>(ei, et, cursor, esrc, E);
  k_seg<<<(N + 3) / 4, 256, 0, stream>>>(start, esrc, xb, mn, N);
  k_gemm<<<(N + 63) / 64, 256, 0, stream>>>(mn, xb, W, root, bias, out, N);
}